// Round 4
// baseline (44.810 us; speedup 1.0000x reference)
//
#include <hip/hip_runtime.h>

// NQ=8 qubits, NL=3 layers, B=65536. 16 lanes per sample, 16 amps/lane.
// idx bits [7:4] = i (register), [3:0] = sub = lane bits [3:0]; lane bits
// [5:4] select the sample within the wave (4 samples/wave).
// Lane wires: wire4 <-> lane^8 (DPP row_ror:8), wire5 <-> lane^4
// (ds_swizzle BitMode xor4), wire6 <-> lane^2 (DPP 0x4E), wire7 <-> lane^1
// (DPP 0xB1). Register wires 0..3 <-> i bits 3..0.
// Layer-0 RYs act on a product state -> folded analytically into the init
// product tree. Layer-2 RZZ diag is a pure phase -> skipped.

typedef float v2f __attribute__((ext_vector_type(2)));

__device__ __forceinline__ v2f splat(float x) { v2f r; r.x = x; r.y = x; return r; }

template <int CTRL>
__device__ __forceinline__ float dppf(float x) {
    return __int_as_float(
        __builtin_amdgcn_mov_dpp(__float_as_int(x), CTRL, 0xF, 0xF, true));
}
template <int CTRL>
__device__ __forceinline__ v2f dpp2(v2f a) {
    v2f r; r.x = dppf<CTRL>(a.x); r.y = dppf<CTRL>(a.y); return r;
}

__device__ __forceinline__ float swz4(float x) {   // lane ^ 4
    return __int_as_float(
        __builtin_amdgcn_ds_swizzle(__float_as_int(x), 0x101F));
}
__device__ __forceinline__ v2f swz4v(v2f a) {
    v2f r; r.x = swz4(a.x); r.y = swz4(a.y); return r;
}

__device__ __forceinline__ v2f cmul(v2f a, v2f b) {
    v2f r;
    r.x = a.x * b.x - a.y * b.y;
    r.y = a.x * b.y + a.y * b.x;
    return r;
}

#define DPP_XOR1 0xB1   // quad_perm [1,0,3,2]
#define DPP_XOR2 0x4E   // quad_perm [2,3,0,1]
#define DPP_XOR8 0x128  // row_ror:8 == lane^8 within a 16-lane row

__global__ __launch_bounds__(256, 4)
void qsim_kernel(const float* __restrict__ w, const float* __restrict__ z1,
                 const float* __restrict__ z2, float* __restrict__ out,
                 int nsamp) {
    __shared__ v2f s_diag[2][256];  // RZZ diagonal, layers 0..1: exp(-0.5i*ang)
    __shared__ v2f s_cs[3][8];      // (cos, sin) of weights[l][q]/2

    const int t = threadIdx.x;

    #pragma unroll
    for (int l = 0; l < 2; ++l) {
        float ang = 0.f;
        #pragma unroll
        for (int i = 0; i < 7; ++i) {
            // zz_i(idx) = +1 if idx bits (7-i),(6-i) equal else -1
            float zz = (((t >> (7 - i)) ^ (t >> (6 - i))) & 1) ? -1.f : 1.f;
            ang = fmaf(w[l * 15 + 8 + i], zz, ang);
        }
        float sv, cv;
        __sincosf(0.5f * ang, &sv, &cv);
        v2f d; d.x = cv; d.y = -sv;        // exp(-0.5 i ang)
        s_diag[l][t] = d;
    }
    if (t < 24) {
        int l = t >> 3, q = t & 7;
        float a = 0.5f * w[l * 15 + q];
        v2f cs; cs.x = __cosf(a); cs.y = __sinf(a);
        s_cs[l][q] = cs;
    }
    __syncthreads();

    const int lane = t & 63;
    const int sub = lane & 15;                        // idx bits [3:0]
    const int s = blockIdx.x * 16 + ((t >> 6) << 2) + (lane >> 4);
    if (s >= nsamp) return;

    // ---- per-wire single-qubit state after layer-0 RY (product state)
    // |0> -> RY(asin z1) -> RZ(asin z2): v0 = cos(a1/2) e^{-i a2/2},
    //                                    v1 = sin(a1/2) e^{+i a2/2}
    const float z1v = z1[s], z2v = z2[s];
    const float u1 = sqrtf(fmaxf(0.f, 1.f - z1v * z1v));  // cos a1
    const float u2 = sqrtf(fmaxf(0.f, 1.f - z2v * z2v));  // cos a2
    const float c1 = sqrtf(0.5f * (1.f + u1));
    const float s1v = copysignf(sqrtf(fmaxf(0.f, 0.5f * (1.f - u1))), z1v);
    const float ch = sqrtf(0.5f * (1.f + u2));
    const float sh = copysignf(sqrtf(fmaxf(0.f, 0.5f * (1.f - u2))), z2v);
    v2f v0; v0.x = c1 * ch;  v0.y = -c1 * sh;
    v2f v1; v1.x = s1v * ch; v1.y = s1v * sh;

    // Apply layer-0 RY(w[0][q]) per wire: A=alpha (bit=0), Bt=beta (bit=1)
    v2f A[8], Bt[8];
    #pragma unroll
    for (int q = 0; q < 8; ++q) {
        const v2f cs = s_cs[0][q];
        A[q]  = splat(cs.x) * v0 - splat(cs.y) * v1;
        Bt[q] = splat(cs.y) * v0 + splat(cs.x) * v1;
    }

    // Lane-wire factor (wires 4,5,6,7 <-> lane bits 3,2,1,0), then product
    // tree over register wires (i bit k <-> wire 3-k).
    v2f amp[16];
    amp[0] = cmul(cmul((lane & 8) ? Bt[4] : A[4], (lane & 4) ? Bt[5] : A[5]),
                  cmul((lane & 2) ? Bt[6] : A[6], (lane & 1) ? Bt[7] : A[7]));
    #pragma unroll
    for (int k = 0; k < 4; ++k) {
        const v2f Aq = A[3 - k], Bq = Bt[3 - k];
        #pragma unroll
        for (int j = 0; j < (1 << k); ++j) {
            amp[j | (1 << k)] = cmul(amp[j], Bq);
            amp[j]            = cmul(amp[j], Aq);
        }
    }

    // ---- entangler diag 0, RY layer 1, diag 1, RY layer 2
    #pragma unroll
    for (int i = 0; i < 16; ++i)
        amp[i] = cmul(amp[i], s_diag[0][(i << 4) | sub]);

    #pragma unroll
    for (int l = 1; l < 3; ++l) {
        // register wires 0..3 (i bit 3-q)
        #pragma unroll
        for (int q = 0; q < 4; ++q) {
            const int b = 3 - q;
            const v2f cs = s_cs[l][q];
            const v2f cq = splat(cs.x), sq = splat(cs.y);
            #pragma unroll
            for (int h = 0; h < 8; ++h) {
                const int lm = (1 << b) - 1;
                const int i0 = ((h & ~lm) << 1) | (h & lm);
                const int i1 = i0 | (1 << b);
                const v2f a0 = amp[i0], a1 = amp[i1];
                amp[i0] = cq * a0 - sq * a1;
                amp[i1] = sq * a0 + cq * a1;
            }
        }
        // wire 4: lane xor 8 (DPP row_ror:8)
        {
            const v2f cs = s_cs[l][4];
            const v2f cq = splat(cs.x);
            const v2f se = splat((lane & 8) ? cs.y : -cs.y);
            #pragma unroll
            for (int i = 0; i < 16; ++i)
                amp[i] = cq * amp[i] + se * dpp2<DPP_XOR8>(amp[i]);
        }
        // wire 5: lane xor 4 (ds_swizzle)
        {
            const v2f cs = s_cs[l][5];
            const v2f cq = splat(cs.x);
            const v2f se = splat((lane & 4) ? cs.y : -cs.y);
            #pragma unroll
            for (int i = 0; i < 16; ++i)
                amp[i] = cq * amp[i] + se * swz4v(amp[i]);
        }
        // wire 6: lane xor 2 (DPP)
        {
            const v2f cs = s_cs[l][6];
            const v2f cq = splat(cs.x);
            const v2f se = splat((lane & 2) ? cs.y : -cs.y);
            #pragma unroll
            for (int i = 0; i < 16; ++i)
                amp[i] = cq * amp[i] + se * dpp2<DPP_XOR2>(amp[i]);
        }
        // wire 7: lane xor 1 (DPP)
        {
            const v2f cs = s_cs[l][7];
            const v2f cq = splat(cs.x);
            const v2f se = splat((lane & 1) ? cs.y : -cs.y);
            #pragma unroll
            for (int i = 0; i < 16; ++i)
                amp[i] = cq * amp[i] + se * dpp2<DPP_XOR1>(amp[i]);
        }
        if (l == 1) {
            #pragma unroll
            for (int i = 0; i < 16; ++i)
                amp[i] = cmul(amp[i], s_diag[1][(i << 4) | sub]);
        }
        // l==2: diag is a pure phase before |.|^2 -> skip
    }

    // ---- probabilities + signed sums
    float pr[16];
    #pragma unroll
    for (int i = 0; i < 16; ++i)
        pr[i] = fmaf(amp[i].x, amp[i].x, amp[i].y * amp[i].y);

    float S[8];
    #pragma unroll
    for (int q = 0; q < 4; ++q) {        // register wires, MSB-first peel
        const int half = 8 >> q;
        float d = 0.f;
        #pragma unroll
        for (int j = 0; j < half; ++j) {
            d += pr[j] - pr[j + half];
            pr[j] += pr[j + half];
        }
        S[q] = d;
    }
    const float T = pr[0];               // lane-local probability mass
    S[4] = (lane & 8) ? -T : T;
    S[5] = (lane & 4) ? -T : T;
    S[6] = (lane & 2) ? -T : T;
    S[7] = (lane & 1) ? -T : T;

    // butterfly over the sample's 16 lanes (lane bits 0,1,2,3)
    #pragma unroll
    for (int k = 0; k < 8; ++k) {
        S[k] += dppf<DPP_XOR1>(S[k]);
        S[k] += dppf<DPP_XOR2>(S[k]);
        S[k] += swz4(S[k]);
        S[k] += dppf<DPP_XOR8>(S[k]);
    }

    // lanes with sub<8 write out[s*8 + sub] = S[sub] (mux-select S[lane&7])
    const float m01 = (lane & 1) ? S[1] : S[0];
    const float m23 = (lane & 1) ? S[3] : S[2];
    const float m45 = (lane & 1) ? S[5] : S[4];
    const float m67 = (lane & 1) ? S[7] : S[6];
    const float n03 = (lane & 2) ? m23 : m01;
    const float n47 = (lane & 2) ? m67 : m45;
    const float r   = (lane & 4) ? n47 : n03;
    if ((lane & 8) == 0)
        out[(size_t)s * 8 + (lane & 7)] = r;
}

extern "C" void kernel_launch(void* const* d_in, const int* in_sizes, int n_in,
                              void* d_out, int out_size, void* d_ws,
                              size_t ws_size, hipStream_t stream) {
    const float* w  = (const float*)d_in[0];   // (3, 15) f32
    const float* z1 = (const float*)d_in[1];   // (B,)   f32
    const float* z2 = (const float*)d_in[2];   // (B,)   f32
    float* out = (float*)d_out;                // (B, 8) f32

    const int n = in_sizes[1];
    const int blocks = (n * 16 + 255) / 256;
    qsim_kernel<<<blocks, 256, 0, stream>>>(w, z1, z2, out, n);
}

// Round 5
// 30.855 us; speedup vs baseline: 1.4523x; 1.4523x over previous
//
#include <hip/hip_runtime.h>

// NQ=8, NL=3, B=65536. Algebraic collapse:
//   psi0_k = v0^8 * t^popcount(k), t = tan(a1/2) e^{i a2}  (rank-9 batch structure)
//   C = U * P   (256x9 complex; P = popcount-class selector; U = circuit w/o
//                final diagonal, which cancels in |.|^2)
//   out_q = q1^8 * sum_{m,m'} G^q_{mm'} t^m conj(t)^m',  G^q = C^H diag(ZV_q) C
//   with u = |t|^2 = tan^2(a1/2):
//   out_q = q1^8 * [ A^q(u) + sum_{d=1..8} Re(t^d) ReB^q_d(u) - Im(t^d) ImB^q_d(u) ]
// ws layout: C = 256*9 float2 (18432 B) @0;  G = 8*81 floats (2592 B) @18432.

#define G_OFF 18432

// ---------------- k1: build C (9 blocks = popcount classes, 256 thr = j) ----
__global__ void build_C(const float* __restrict__ w, float2* __restrict__ C) {
    const int m = blockIdx.x;      // 0..8
    const int j = threadIdx.x;     // basis index 0..255
    __shared__ float2 xch[256];

    float ar = (__popc(j) == m) ? 1.f : 0.f;
    float ai = 0.f;

    for (int l = 0; l < 3; ++l) {
        for (int q = 0; q < 8; ++q) {
            const int b = 7 - q;               // wire q <-> bit (7-q)
            float sv, cv;
            __sincosf(0.5f * w[l * 15 + q], &sv, &cv);
            float pr, pi;
            if (b >= 6) {                      // cross-wave: LDS exchange
                xch[j] = make_float2(ar, ai);
                __syncthreads();
                float2 p = xch[j ^ (1 << b)];
                __syncthreads();
                pr = p.x; pi = p.y;
            } else {                           // in-wave: shuffle
                pr = __shfl_xor(ar, 1 << b, 64);
                pi = __shfl_xor(ai, 1 << b, 64);
            }
            const float sg = ((j >> b) & 1) ? sv : -sv;
            ar = cv * ar + sg * pr;
            ai = cv * ai + sg * pi;
        }
        if (l < 2) {                           // RZZ diagonal (skip final one)
            float ang = 0.f;
            for (int i = 0; i < 7; ++i) {
                float zz = (((j >> (7 - i)) ^ (j >> (6 - i))) & 1) ? -1.f : 1.f;
                ang = fmaf(w[l * 15 + 8 + i], zz, ang);
            }
            float s2, c2;
            __sincosf(0.5f * ang, &s2, &c2);   // amp *= exp(-0.5 i ang)
            const float nr = ar * c2 + ai * s2;
            const float ni = ai * c2 - ar * s2;
            ar = nr; ai = ni;
        }
    }
    C[(size_t)j * 9 + m] = make_float2(ar, ai);
}

// ---------------- k2: build G (8 blocks = qubits, 256 thr = j) --------------
// per q: 81 floats: [0..8]=diag G_mm; then d=1..8, k=0..8-d: (2*G_{k+d,k}) re,im
__global__ void build_G(const float2* __restrict__ C, float* __restrict__ g) {
    const int q = blockIdx.x;
    const int j = threadIdx.x;
    const int lane = j & 63, wv = j >> 6;
    __shared__ float red[4][81];

    float2 Cv[9];
    #pragma unroll
    for (int k = 0; k < 9; ++k) Cv[k] = C[(size_t)j * 9 + k];

    const float sg = ((j >> (7 - q)) & 1) ? -1.f : 1.f;
    float v[81];
    #pragma unroll
    for (int m = 0; m < 9; ++m)
        v[m] = sg * (Cv[m].x * Cv[m].x + Cv[m].y * Cv[m].y);
    {
        const float f = 2.f * sg;
        int idx = 9;
        #pragma unroll
        for (int d = 1; d <= 8; ++d) {
            #pragma unroll
            for (int k = 0; k + d <= 8; ++k) {
                const float2 hi = Cv[k + d], lo = Cv[k];   // hi * conj(lo)
                v[idx++] = f * (hi.x * lo.x + hi.y * lo.y);
                v[idx++] = f * (hi.y * lo.x - hi.x * lo.y);
            }
        }
    }
    #pragma unroll
    for (int st = 1; st < 64; st <<= 1) {
        #pragma unroll
        for (int i = 0; i < 81; ++i) v[i] += __shfl_xor(v[i], st, 64);
    }
    if (lane == 0) {
        #pragma unroll
        for (int i = 0; i < 81; ++i) red[wv][i] = v[i];
    }
    __syncthreads();
    if (j < 81)
        g[q * 81 + j] = red[0][j] + red[1][j] + red[2][j] + red[3][j];
}

// ---------------- k3: batch evaluation (1 sample per lane) ------------------
__global__ __launch_bounds__(256)
void batch_eval(const float* __restrict__ g, const float* __restrict__ z1,
                const float* __restrict__ z2, float* __restrict__ out,
                int nsamp) {
    const int s = blockIdx.x * 256 + threadIdx.x;
    if (s >= nsamp) return;

    const float z1v = z1[s], z2v = z2[s];
    const float u1 = sqrtf(fmaxf(0.f, 1.f - z1v * z1v));   // cos a1
    const float q1 = 0.5f * (1.f + u1);                     // cos^2(a1/2) >= .5
    const float s1 = copysignf(sqrtf(fmaxf(0.f, 0.5f * (1.f - u1))), z1v);
    const float tn = s1 * rsqrtf(q1);                       // tan(a1/2)
    const float u2 = sqrtf(fmaxf(0.f, 1.f - z2v * z2v));    // cos a2
    const float tr = tn * u2, ti = tn * z2v;                // t = tn e^{i a2}
    const float u  = tn * tn;                               // |t|^2
    float w8 = q1 * q1; w8 *= w8; w8 *= w8;                 // q1^8 = |v0|^16

    float Tr[9], Ti[9];
    Tr[1] = tr; Ti[1] = ti;
    #pragma unroll
    for (int d = 2; d <= 8; ++d) {
        Tr[d] = Tr[d - 1] * tr - Ti[d - 1] * ti;
        Ti[d] = Tr[d - 1] * ti + Ti[d - 1] * tr;
    }

    float o[8];
    #pragma unroll
    for (int q = 0; q < 8; ++q) {
        const float* gq = g + q * 81;        // uniform address -> s_load
        float r = gq[8];
        #pragma unroll
        for (int m = 7; m >= 0; --m) r = fmaf(r, u, gq[m]);
        int off = 9;
        #pragma unroll
        for (int d = 1; d <= 8; ++d) {
            const int K = 8 - d;             // poly degree in u
            float br = gq[off + 2 * K], bi = gq[off + 2 * K + 1];
            #pragma unroll
            for (int k = K - 1; k >= 0; --k) {
                br = fmaf(br, u, gq[off + 2 * k]);
                bi = fmaf(bi, u, gq[off + 2 * k + 1]);
            }
            r = fmaf(Tr[d], br, r);
            r = fmaf(-Ti[d], bi, r);
            off += 2 * (K + 1);
        }
        o[q] = w8 * r;
    }

    float4* op = (float4*)(out + (size_t)s * 8);
    op[0] = make_float4(o[0], o[1], o[2], o[3]);
    op[1] = make_float4(o[4], o[5], o[6], o[7]);
}

// ---------------------------------------------------------------------------
extern "C" void kernel_launch(void* const* d_in, const int* in_sizes, int n_in,
                              void* d_out, int out_size, void* d_ws,
                              size_t ws_size, hipStream_t stream) {
    const float* w  = (const float*)d_in[0];   // (3, 15) f32
    const float* z1 = (const float*)d_in[1];   // (B,)   f32
    const float* z2 = (const float*)d_in[2];   // (B,)   f32
    float* out = (float*)d_out;                // (B, 8) f32

    float2* C = (float2*)d_ws;
    float*  g = (float*)((char*)d_ws + G_OFF);

    build_C<<<9, 256, 0, stream>>>(w, C);
    build_G<<<8, 256, 0, stream>>>(C, g);

    const int n = in_sizes[1];
    batch_eval<<<(n + 255) / 256, 256, 0, stream>>>(g, z1, z2, out, n);
}